// Round 2
// baseline (107.850 us; speedup 1.0000x reference)
//
#include <hip/hip_runtime.h>

// BaseModel_3100966387783 — per-variable masked 3-layer MLP, b=8192, D=128, h=64, o=2.
//
// R5: kill the layer-2 MFMA + second LDS round-trip.
//   o=2 padded to a 16-row MFMA was 87.5% dead FLOPs AND forced an extra
//   epi-pack -> ds_write -> ds_read serial segment. Now: out[o][row] is
//   computed straight from acc1 (fp32, in-register): 64 FMA/lane with
//   broadcast-loaded fp32 w2, then xor-16/xor-32 shuffle reduce across the
//   4 lq groups. Removes per wave-iter: 4 MFMA, 8 ds_write_b64,
//   4 ds_read_b128, ~80 VALU of h2 packing, one ~120cy DS latency segment.
//   Prediction: fused_mlp -20..30%; dur_us 105.7 -> 88-97 us.
//
// R3/R4 (verified 105.7-107.4 us): brick layout + register-resident weights
//   + persistent bt-loop, zero barriers, 2 waves/SIMD.
//   brick = 1 KB = 64 lanes x 16 B bf16; lane l holds
//   T[tile*16 + (l&15)][ks*32 + (l>>4)*8 + 0..7] = one MFMA A/B fragment.

typedef __bf16 bf16_t;
typedef __bf16 bf16x8 __attribute__((ext_vector_type(8)));
typedef float  f32x4  __attribute__((ext_vector_type(4)));

#define LEAKY 0.01f

// ---------------- ws brick regions (byte offsets) ----------------
#define XB_OFF   0u                  // x bricks:   64 bt x 8 nt x 4 ks = 2048 bricks
#define W0B_OFF  (2048u*1024u)       // w0 masked: 128 t x 4 it x 4 ks = 2048
#define W1B_OFF  (4096u*1024u)       // w1:        128 t x 4 it x 2 ks = 1024
// total ws need: 5120 KiB (w2 now read as fp32 directly in fused_mlp)

// =================== pre-kernel: fp32 -> bf16 brick-ify ===================
__global__ __launch_bounds__(256)
void brickify(const float* __restrict__ x,  const float* __restrict__ w0,
              const float* __restrict__ w1, unsigned char* __restrict__ ws)
{
    const int wid  = blockIdx.x * 4 + (threadIdx.x >> 6);  // one wave = one brick
    const int lane = threadIdx.x & 63;
    const int lr = lane & 15, lq = lane >> 4;

    float v[8];
    if (wid < 2048) {                        // ---- x bricks ----
        int bt = wid >> 5, rem = wid & 31, nt = rem >> 2, ks = rem & 3;
        const float* s = x + (size_t)(bt*128 + nt*16 + lr) * 128 + ks*32 + lq*8;
        const float4 a = *(const float4*)s, b = *(const float4*)(s + 4);
        v[0]=a.x; v[1]=a.y; v[2]=a.z; v[3]=a.w;
        v[4]=b.x; v[5]=b.y; v[6]=b.z; v[7]=b.w;
    } else if (wid < 4096) {                 // ---- w0 bricks (masked) ----
        int u = wid - 2048, t = u >> 4, rem = u & 15, it = rem >> 2, ks = rem & 3;
        int k0 = ks*32 + lq*8;
        const float* s = w0 + (size_t)(t*64 + it*16 + lr) * 128 + k0;
        const float4 a = *(const float4*)s, b = *(const float4*)(s + 4);
        v[0]=a.x; v[1]=a.y; v[2]=a.z; v[3]=a.w;
        v[4]=b.x; v[5]=b.y; v[6]=b.z; v[7]=b.w;
        #pragma unroll
        for (int j = 0; j < 8; ++j) if (k0 + j == t) v[j] = 0.f;
    } else {                                 // ---- w1 bricks ----
        int u = wid - 4096, t = u >> 3, rem = u & 7, it = rem >> 1, ks = rem & 1;
        const float* s = w1 + (size_t)(t*64 + it*16 + lr) * 64 + ks*32 + lq*8;
        const float4 a = *(const float4*)s, b = *(const float4*)(s + 4);
        v[0]=a.x; v[1]=a.y; v[2]=a.z; v[3]=a.w;
        v[4]=b.x; v[5]=b.y; v[6]=b.z; v[7]=b.w;
    }
    union { bf16_t h[8]; uint4 q; } pk;
    #pragma unroll
    for (int j = 0; j < 8; ++j) pk.h[j] = (bf16_t)v[j];
    ((uint4*)ws)[(size_t)wid * 64 + lane] = pk.q;   // dst = brick*1024 + lane*16
}

// =========================== main fused kernel ===========================
__global__ __launch_bounds__(256, 2)
void fused_mlp(const unsigned char* __restrict__ ws,
               const float* __restrict__ w2,
               const float* __restrict__ b0, const float* __restrict__ b1,
               const float* __restrict__ b2, float* __restrict__ out)
{
    // h bricks only: 8 nt-tiles x 2 ks = 16 bricks, wave-private slices. No barriers.
    __shared__ __align__(16) unsigned char hsm[16384];

    const int tid  = threadIdx.x;
    const int w    = tid >> 6;         // wave 0..3: owns batch rows w*32 .. w*32+31
    const int lane = tid & 63;
    const int lr = lane & 15, lq = lane >> 4;
    const int g  = blockIdx.x;         // batch group: bt = g*8 + s
    const int t  = blockIdx.y;         // variable index

    // ---- weights: global -> registers (L2-hit, coalesced 1 KB/instr) ----
    const unsigned char* w0p = ws + W0B_OFF + (size_t)t*16384 + lane*16;
    const unsigned char* w1p = ws + W1B_OFF + (size_t)t*8192  + lane*16;
    bf16x8 w0f[4][4], w1f[4][2];
    #pragma unroll
    for (int it = 0; it < 4; ++it)
        #pragma unroll
        for (int ks = 0; ks < 4; ++ks)
            w0f[it][ks] = *(const bf16x8*)(w0p + (it*4+ks)*1024);
    #pragma unroll
    for (int it = 0; it < 4; ++it)
        #pragma unroll
        for (int ks = 0; ks < 2; ++ks)
            w1f[it][ks] = *(const bf16x8*)(w1p + (it*2+ks)*1024);

    // ---- w2 as fp32, per-lane slice for the in-register L2 finish ----
    // lane (lq) needs w2[t][o][i2 = it*16 + lq*4 + r]; same addr across the
    // 16 lanes of an lr-group -> broadcast loads, L2-hit.
    f32x4 w2q[2][4];
    #pragma unroll
    for (int o = 0; o < 2; ++o)
        #pragma unroll
        for (int it = 0; it < 4; ++it)
            w2q[o][it] = *(const f32x4*)(w2 + t*128 + o*64 + it*16 + lq*4);

    // ---- biases: per-quad float4 (acc-init form) ----
    f32x4 b0q[4], b1q[4];
    #pragma unroll
    for (int it = 0; it < 4; ++it) {
        b0q[it] = *(const f32x4*)(b0 + t*64 + it*16 + lq*4);
        b1q[it] = *(const f32x4*)(b1 + t*64 + it*16 + lq*4);
    }
    const float2 b2v = *(const float2*)(b2 + t*2);

    // ---- x fragment pointer helper; preload iter 0 ----
    const unsigned char* xp = ws + XB_OFF + lane*16;
    bf16x8 xf[2][4];
    {
        const int bt0 = g*8;
        #pragma unroll
        for (int ntl = 0; ntl < 2; ++ntl)
            #pragma unroll
            for (int ks = 0; ks < 4; ++ks)
                xf[ntl][ks] = *(const bf16x8*)(xp + (size_t)(((bt0*8 + w*2+ntl)*4 + ks))*1024);
    }

    for (int s = 0; s < 8; ++s) {
        const int bt = g*8 + s;

        // ============ layer 0: D0[i][row] = w0m @ x^T (+b0 via C-init) ============
        f32x4 acc0[2][4];
        #pragma unroll
        for (int ntl = 0; ntl < 2; ++ntl)
            #pragma unroll
            for (int it = 0; it < 4; ++it) acc0[ntl][it] = b0q[it];

        #pragma unroll
        for (int ks = 0; ks < 4; ++ks)
            #pragma unroll
            for (int it = 0; it < 4; ++it)
                #pragma unroll
                for (int ntl = 0; ntl < 2; ++ntl)
                    acc0[ntl][it] = __builtin_amdgcn_mfma_f32_16x16x32_bf16(
                                        w0f[it][ks], xf[ntl][ks], acc0[ntl][it], 0, 0, 0);

        // ---- xf now dead: prefetch next iter's fragments into the same regs ----
        {
            const int btn = (s < 7) ? bt + 1 : bt;
            #pragma unroll
            for (int ntl = 0; ntl < 2; ++ntl)
                #pragma unroll
                for (int ks = 0; ks < 4; ++ks)
                    xf[ntl][ks] = *(const bf16x8*)(xp + (size_t)(((btn*8 + w*2+ntl)*4 + ks))*1024);
        }

        // epi0 -> h bricks: C reg r is k = it*16 + lq*4 + r (4 consecutive k) -> one b64
        #pragma unroll
        for (int ntl = 0; ntl < 2; ++ntl)
            #pragma unroll
            for (int it = 0; it < 4; ++it) {
                union { bf16_t h[4]; unsigned long long u; } pk;
                #pragma unroll
                for (int r = 0; r < 4; ++r) {
                    float u = acc0[ntl][it][r];
                    pk.h[r] = (bf16_t)fmaxf(u, LEAKY * u);
                }
                int off = ((w*2+ntl)*2 + (it>>1)) * 1024
                        + (((it&1)*2 + (lq>>1))*16 + lr) * 16 + (lq&1)*8;
                *(unsigned long long*)(hsm + off) = pk.u;
            }

        // ============ layer 1: D1[i2][row] = w1 @ h^T (+b1 via C-init) ============
        bf16x8 hf[2][2];
        #pragma unroll
        for (int ntl = 0; ntl < 2; ++ntl)
            #pragma unroll
            for (int ks = 0; ks < 2; ++ks)
                hf[ntl][ks] = *(const bf16x8*)(hsm + ((w*2+ntl)*2 + ks)*1024 + lane*16);

        f32x4 acc1[2][4];
        #pragma unroll
        for (int ntl = 0; ntl < 2; ++ntl)
            #pragma unroll
            for (int it = 0; it < 4; ++it) acc1[ntl][it] = b1q[it];

        #pragma unroll
        for (int ks = 0; ks < 2; ++ks)
            #pragma unroll
            for (int it = 0; it < 4; ++it)
                #pragma unroll
                for (int ntl = 0; ntl < 2; ++ntl)
                    acc1[ntl][it] = __builtin_amdgcn_mfma_f32_16x16x32_bf16(
                                        w1f[it][ks], hf[ntl][ks], acc1[ntl][it], 0, 0, 0);

        // ============ layer 2 (o=2) — in-register VALU finish ============
        // out[o][row] = sum_i2 w2[o][i2] * leaky(acc1[i2][row]) + b2[o]
        // lane holds i2 = it*16 + lq*4 + r for row = lr; partial over this
        // lane's 16 i2, then xor-16/xor-32 reduce across the 4 lq groups.
        #pragma unroll
        for (int ntl = 0; ntl < 2; ++ntl) {
            float p0 = 0.f, p1 = 0.f;
            #pragma unroll
            for (int it = 0; it < 4; ++it)
                #pragma unroll
                for (int r = 0; r < 4; ++r) {
                    float u = acc1[ntl][it][r];
                    float a = fmaxf(u, LEAKY * u);
                    p0 = fmaf(w2q[0][it][r], a, p0);
                    p1 = fmaf(w2q[1][it][r], a, p1);
                }
            p0 += __shfl_xor(p0, 16); p0 += __shfl_xor(p0, 32);
            p1 += __shfl_xor(p1, 16); p1 += __shfl_xor(p1, 32);
            if (lq == 0) {
                int row = bt*128 + (w*2+ntl)*16 + lr;
                float2 o2 = { p0 + b2v.x, p1 + b2v.y };
                *(float2*)(out + (size_t)row*256 + t*2) = o2;
            }
        }
    }
}

extern "C" void kernel_launch(void* const* d_in, const int* in_sizes, int n_in,
                              void* d_out, int out_size, void* d_ws, size_t ws_size,
                              hipStream_t stream) {
    const float* x  = (const float*)d_in[0];
    const float* w0 = (const float*)d_in[1];
    const float* w1 = (const float*)d_in[2];
    const float* w2 = (const float*)d_in[3];
    const float* b0 = (const float*)d_in[4];
    const float* b1 = (const float*)d_in[5];
    const float* b2 = (const float*)d_in[6];
    unsigned char* ws = (unsigned char*)d_ws;   // needs 5120 KiB
    float* out = (float*)d_out;

    brickify<<<dim3(1280), dim3(256), 0, stream>>>(x, w0, w1, ws);
    // grid (8 batch-groups, 128 t): 1024 blocks; XCD = blockid%8 = g, so each
    // XCD sees one group's x bricks (256 KB) + all weights (3 MB) -> fits 4 MB L2.
    fused_mlp<<<dim3(8, 128), dim3(256), 0, stream>>>(ws, w2, b0, b1, b2, out);
}